// Round 3
// baseline (3187.064 us; speedup 1.0000x reference)
//
#include <hip/hip_runtime.h>
#include <hip/hip_bf16.h>

#define Bn 256
#define Tn 1024
#define Dn 64
#define Hn 128
#define G3 384
#define ICn 100
#define NTH 384

__device__ __forceinline__ float rl(float v, int k) {
    return __uint_as_float(__builtin_amdgcn_readlane(__float_as_uint(v), k));
}
__device__ __forceinline__ float sigm(float x) { return 1.0f / (1.0f + expf(-x)); }

// ---------------- Encoder GRU ----------------
// One WG per batch element. Thread g owns gate-row g (of 384): holds
// We_hh[g,0:128] and We_ih[g,0:64] in VGPRs. h broadcast via v_readlane.
__global__ __launch_bounds__(NTH, 2)
void enc_kernel(const float* __restrict__ mu,
                const float* __restrict__ We_ih,
                const float* __restrict__ We_hh,
                const float* __restrict__ be_ih,
                const float* __restrict__ be_hh,
                float* __restrict__ h_enc)
{
    const int b = blockIdx.x;
    const int g = threadIdx.x;
    const int lane = g & 63;

    float whh[Hn];
    float wih[Dn];
    {
        const float4* p = reinterpret_cast<const float4*>(We_hh + (size_t)g * Hn);
#pragma unroll
        for (int k = 0; k < Hn / 4; ++k) {
            float4 v = p[k];
            whh[4*k+0] = v.x; whh[4*k+1] = v.y; whh[4*k+2] = v.z; whh[4*k+3] = v.w;
        }
        const float4* q = reinterpret_cast<const float4*>(We_ih + (size_t)g * Dn);
#pragma unroll
        for (int k = 0; k < Dn / 4; ++k) {
            float4 v = q[k];
            wih[4*k+0] = v.x; wih[4*k+1] = v.y; wih[4*k+2] = v.z; wih[4*k+3] = v.w;
        }
    }
    const float bih = be_ih[g];
    const float bhh = be_hh[g];

    __shared__ float h[Hn];
    __shared__ float xs[2][4][Dn];   // double-buffered 4-timestep chunks of mu
    __shared__ float xp[G3];
    __shared__ float hp[G3];

    if (g < Hn) h[g] = 0.0f;

    const float* mu_b = mu + (size_t)b * Tn * Dn;

    // preload chunk 0 (4 steps x 64 dims = 256 floats)
    if (g < 256) xs[0][g >> 6][g & 63] = mu_b[g];

    const int NCH = Tn / 4;
    for (int ch = 0; ch < NCH; ++ch) {
        const int buf = ch & 1;
        // issue prefetch of next chunk early; consumed (LDS write) at chunk end
        float pre = 0.0f;
        const bool do_pre = (ch + 1 < NCH) && (g < 256);
        if (do_pre) pre = mu_b[(size_t)(ch + 1) * 256 + g];

#pragma unroll
        for (int s = 0; s < 4; ++s) {
            __syncthreads();  // A: h update + staged x visible
            float hA = h[lane];
            float hB = h[64 + lane];
            float xA = xs[buf][s][lane];

            float a0 = 0.f, a1 = 0.f, a2 = 0.f, a3 = 0.f;
#pragma unroll
            for (int k = 0; k < 64; k += 4) {
                a0 = fmaf(whh[k+0], rl(hA, k+0), a0);
                a1 = fmaf(whh[k+1], rl(hA, k+1), a1);
                a2 = fmaf(whh[k+2], rl(hA, k+2), a2);
                a3 = fmaf(whh[k+3], rl(hA, k+3), a3);
            }
#pragma unroll
            for (int k = 0; k < 64; k += 4) {
                a0 = fmaf(whh[64+k+0], rl(hB, k+0), a0);
                a1 = fmaf(whh[64+k+1], rl(hB, k+1), a1);
                a2 = fmaf(whh[64+k+2], rl(hB, k+2), a2);
                a3 = fmaf(whh[64+k+3], rl(hB, k+3), a3);
            }
            const float hpart = bhh + ((a0 + a1) + (a2 + a3));

            float c0 = 0.f, c1 = 0.f, c2 = 0.f, c3 = 0.f;
#pragma unroll
            for (int k = 0; k < 64; k += 4) {
                c0 = fmaf(wih[k+0], rl(xA, k+0), c0);
                c1 = fmaf(wih[k+1], rl(xA, k+1), c1);
                c2 = fmaf(wih[k+2], rl(xA, k+2), c2);
                c3 = fmaf(wih[k+3], rl(xA, k+3), c3);
            }
            const float xpart = bih + ((c0 + c1) + (c2 + c3));

            hp[g] = hpart;
            xp[g] = xpart;
            __syncthreads();  // B: hp/xp visible
            if (g < Hn) {
                float r = sigm(xp[g] + hp[g]);
                float z = sigm(xp[Hn + g] + hp[Hn + g]);
                float n = tanhf(xp[2 * Hn + g] + r * hp[2 * Hn + g]);
                h[g] = (1.0f - z) * n + z * h[g];
            }
        }
        // stash prefetched chunk into the other buffer (next chunk's A orders it)
        if (do_pre) xs[buf ^ 1][g >> 6][g & 63] = pre;
    }
    __syncthreads();
    if (g < Hn) h_enc[(size_t)b * Hn + g] = h[g];
}

// ---------------- Generator GRU + fused readout ----------------
__global__ __launch_bounds__(NTH, 2)
void gen_kernel(const float* __restrict__ h_enc,
                const float* __restrict__ W_ic, const float* __restrict__ b_ic,
                const float* __restrict__ Wg_ih, const float* __restrict__ bg_ih,
                const float* __restrict__ Wg_hh, const float* __restrict__ bg_hh,
                const float* __restrict__ W_gf, const float* __restrict__ b_gf,
                const float* __restrict__ W_fr, const float* __restrict__ b_fr,
                float* __restrict__ out)
{
    const int b = blockIdx.x;
    const int g = threadIdx.x;
    const int lane = g & 63;
    const int wid = g >> 6;

    float whh[Hn];
    {
        const float4* p = reinterpret_cast<const float4*>(Wg_hh + (size_t)g * Hn);
#pragma unroll
        for (int k = 0; k < Hn / 4; ++k) {
            float4 v = p[k];
            whh[4*k+0] = v.x; whh[4*k+1] = v.y; whh[4*k+2] = v.z; whh[4*k+3] = v.w;
        }
    }
    const float bhh = bg_hh[g];

    __shared__ float h[Hn];
    __shared__ float ics[ICn];
    __shared__ float xpc[G3];
    __shared__ float hp[G3];
    __shared__ float fred[2][3];

    if (g < Hn) h[g] = h_enc[(size_t)b * Hn + g];
    __syncthreads();

    // IC = h_enc @ W_ic.T + b_ic
    if (g < ICn) {
        float a = b_ic[g];
        const float* wr = W_ic + (size_t)g * Hn;
#pragma unroll 8
        for (int k = 0; k < Hn; ++k) a = fmaf(wr[k], h[k], a);
        ics[g] = a;
    }
    __syncthreads();

    // ic_proj (constant per step) -> LDS
    {
        float a = bg_ih[g];
        const float* wr = Wg_ih + (size_t)g * ICn;
#pragma unroll 4
        for (int k = 0; k < ICn; ++k) a = fmaf(wr[k], ics[k], a);
        xpc[g] = a;
    }

    // readout constants
    float wgf0 = 0.f, wgf1 = 0.f, wgf2 = 0.f;
    if (g < Hn) { wgf0 = W_gf[g]; wgf1 = W_gf[Hn + g]; wgf2 = W_gf[2 * Hn + g]; }
    float wfr0 = 0.f, wfr1 = 0.f, wfr2 = 0.f, bfr = 0.f;
    if (g < Dn) { wfr0 = W_fr[3*g]; wfr1 = W_fr[3*g+1]; wfr2 = W_fr[3*g+2]; bfr = b_fr[g]; }
    const float bgf0 = b_gf[0], bgf1 = b_gf[1], bgf2 = b_gf[2];

    float* outb = out + (size_t)b * Tn * Dn;

    for (int t = 0; t < Tn; ++t) {
        __syncthreads();  // A (covers prologue on t==0, h update from t-1)
        float hA = h[lane];
        float hB = h[64 + lane];
        float a0 = 0.f, a1 = 0.f, a2 = 0.f, a3 = 0.f;
#pragma unroll
        for (int k = 0; k < 64; k += 4) {
            a0 = fmaf(whh[k+0], rl(hA, k+0), a0);
            a1 = fmaf(whh[k+1], rl(hA, k+1), a1);
            a2 = fmaf(whh[k+2], rl(hA, k+2), a2);
            a3 = fmaf(whh[k+3], rl(hA, k+3), a3);
        }
#pragma unroll
        for (int k = 0; k < 64; k += 4) {
            a0 = fmaf(whh[64+k+0], rl(hB, k+0), a0);
            a1 = fmaf(whh[64+k+1], rl(hB, k+1), a1);
            a2 = fmaf(whh[64+k+2], rl(hB, k+2), a2);
            a3 = fmaf(whh[64+k+3], rl(hB, k+3), a3);
        }
        hp[g] = bhh + ((a0 + a1) + (a2 + a3));
        __syncthreads();  // B
        if (g < Hn) {
            float r = sigm(xpc[g] + hp[g]);
            float z = sigm(xpc[Hn + g] + hp[Hn + g]);
            float n = tanhf(xpc[2 * Hn + g] + r * hp[2 * Hn + g]);
            float hn = (1.0f - z) * n + z * h[g];
            h[g] = hn;
            // factors partials: reduce hn * W_gf[f,:] over the two h-waves
            float v0 = hn * wgf0, v1 = hn * wgf1, v2 = hn * wgf2;
#pragma unroll
            for (int off = 32; off >= 1; off >>= 1) {
                v0 += __shfl_down(v0, off, 64);
                v1 += __shfl_down(v1, off, 64);
                v2 += __shfl_down(v2, off, 64);
            }
            if (lane == 0) { fred[wid][0] = v0; fred[wid][1] = v1; fred[wid][2] = v2; }
        }
        __syncthreads();  // C
        if (g < Dn) {
            float f0 = fred[0][0] + fred[1][0] + bgf0;
            float f1 = fred[0][1] + fred[1][1] + bgf1;
            float f2 = fred[0][2] + fred[1][2] + bgf2;
            float rate = bfr + expf(f0) * wfr0 + expf(f1) * wfr1 + expf(f2) * wfr2;
            outb[(size_t)t * Dn + g] = rate;
        }
    }
}

extern "C" void kernel_launch(void* const* d_in, const int* in_sizes, int n_in,
                              void* d_out, int out_size, void* d_ws, size_t ws_size,
                              hipStream_t stream) {
    const float* mu    = (const float*)d_in[0];
    const float* We_ih = (const float*)d_in[1];
    const float* We_hh = (const float*)d_in[2];
    const float* be_ih = (const float*)d_in[3];
    const float* be_hh = (const float*)d_in[4];
    const float* W_ic  = (const float*)d_in[5];
    const float* b_ic  = (const float*)d_in[6];
    const float* Wg_ih = (const float*)d_in[7];   // setup_inputs order!
    const float* Wg_hh = (const float*)d_in[8];
    const float* bg_ih = (const float*)d_in[9];
    const float* bg_hh = (const float*)d_in[10];
    const float* W_gf  = (const float*)d_in[11];
    const float* b_gf  = (const float*)d_in[12];
    const float* W_fr  = (const float*)d_in[13];
    const float* b_fr  = (const float*)d_in[14];

    float* h_enc = (float*)d_ws;  // [B, H] f32 = 128 KiB
    float* out = (float*)d_out;

    enc_kernel<<<dim3(Bn), dim3(NTH), 0, stream>>>(mu, We_ih, We_hh, be_ih, be_hh, h_enc);
    gen_kernel<<<dim3(Bn), dim3(NTH), 0, stream>>>(h_enc, W_ic, b_ic, Wg_ih, bg_ih,
                                                   Wg_hh, bg_hh, W_gf, b_gf, W_fr, b_fr, out);
}

// Round 4
// 1952.208 us; speedup vs baseline: 1.6325x; 1.6325x over previous
//
#include <hip/hip_runtime.h>
#include <hip/hip_bf16.h>

#define Bn 256
#define Tn 1024
#define Dn 64
#define Hn 128
#define G3 384
#define ICn 100
#define BT 16
#define NTH 256
#define LDH 136
#define LDX 72

typedef _Float16 f16;
typedef __attribute__((ext_vector_type(8))) _Float16 f16x8;
typedef __attribute__((ext_vector_type(4))) _Float16 f16x4;
typedef __attribute__((ext_vector_type(4))) float f32x4;

#define MFMA(a, b, c) __builtin_amdgcn_mfma_f32_16x16x32_f16((a), (b), (c), 0, 0, 0)

__device__ __forceinline__ float rcpa(float x) { return __builtin_amdgcn_rcpf(x); }
__device__ __forceinline__ float sigm(float x) { return rcpa(1.0f + __expf(-x)); }
__device__ __forceinline__ float tanha(float x) {
    float t = __expf(-2.0f * x);
    return fmaf(2.0f, rcpa(1.0f + t), -1.0f);
}

// load a B^T fragment (8 contiguous k) from a row-major f32 weight, cvt to f16
__device__ __forceinline__ f16x8 ldw(const float* W, int row, int ldk, int k0) {
    const float* p = W + (size_t)row * ldk + k0;
    f16x8 r;
#pragma unroll
    for (int j = 0; j < 8; ++j) r[j] = (f16)p[j];
    return r;
}

// ---------------- Encoder GRU (MFMA) ----------------
// 16 WGs x 256 threads (4 waves). Wave w owns N-tiles {w+4j}, j=0..5:
// j=0,1 -> r gates, 2,3 -> z, 4,5 -> n; grp = j&1 selects hidx half.
__global__ __launch_bounds__(NTH, 1)
void enc_kernel(const float* __restrict__ mu,
                const float* __restrict__ We_ih, const float* __restrict__ We_hh,
                const float* __restrict__ be_ih, const float* __restrict__ be_hh,
                float* __restrict__ h_enc)
{
    const int b0 = blockIdx.x * BT;
    const int tid = threadIdx.x;
    const int w = tid >> 6, l = tid & 63, c = l & 15, q = l >> 4;

    __shared__ f16 hbuf[2][BT * LDH];
    __shared__ f16 xstg[2][8][BT * LDX];

    f16x8 whf[6][4], wxf[6][2];
    int gidx[6];
#pragma unroll
    for (int j = 0; j < 6; ++j) {
        int g = (w + 4 * j) * 16 + c;
        gidx[j] = g;
#pragma unroll
        for (int kt = 0; kt < 4; ++kt) whf[j][kt] = ldw(We_hh, g, Hn, kt * 32 + q * 8);
#pragma unroll
        for (int kt = 0; kt < 2; ++kt) wxf[j][kt] = ldw(We_ih, g, Dn, kt * 32 + q * 8);
    }
    float brz[4], bxn[2], bhn[2];
#pragma unroll
    for (int j = 0; j < 4; ++j) brz[j] = be_ih[gidx[j]] + be_hh[gidx[j]];
#pragma unroll
    for (int grp = 0; grp < 2; ++grp) { bxn[grp] = be_ih[gidx[4 + grp]]; bhn[grp] = be_hh[gidx[4 + grp]]; }

    float hreg[2][4];
#pragma unroll
    for (int grp = 0; grp < 2; ++grp)
#pragma unroll
        for (int r4 = 0; r4 < 4; ++r4) hreg[grp][r4] = 0.0f;
    for (int i = tid; i < BT * Hn; i += NTH) hbuf[0][(i >> 7) * LDH + (i & 127)] = (f16)0.0f;

    // stage chunk 0 (t = 0..7)
    {
#pragma unroll
        for (int i = 0; i < 8; ++i) {
            int f = (i * NTH + tid) * 4;
            int t_off = f >> 10, rem = f & 1023;
            int bb = rem >> 6, d = rem & 63;
            const float4 v = *reinterpret_cast<const float4*>(
                mu + ((size_t)(b0 + bb) * Tn + t_off) * Dn + d);
            f16x4 h4; h4[0] = (f16)v.x; h4[1] = (f16)v.y; h4[2] = (f16)v.z; h4[3] = (f16)v.w;
            *reinterpret_cast<f16x4*>(&xstg[0][t_off][bb * LDX + d]) = h4;
        }
    }
    __syncthreads();

    float4 pre[8];
    for (int t = 0; t < Tn; ++t) {
        const int ch = t >> 3, s = t & 7, cur = t & 1, sb = ch & 1;
        if (s == 0 && ch + 1 < Tn / 8) {
#pragma unroll
            for (int i = 0; i < 8; ++i) {
                int f = (i * NTH + tid) * 4;
                int t_off = f >> 10, rem = f & 1023;
                int bb = rem >> 6, d = rem & 63;
                pre[i] = *reinterpret_cast<const float4*>(
                    mu + ((size_t)(b0 + bb) * Tn + (ch + 1) * 8 + t_off) * Dn + d);
            }
        }
        f16x8 ah[4], ax[2];
#pragma unroll
        for (int kt = 0; kt < 4; ++kt)
            ah[kt] = *reinterpret_cast<const f16x8*>(&hbuf[cur][c * LDH + kt * 32 + q * 8]);
#pragma unroll
        for (int kt = 0; kt < 2; ++kt)
            ax[kt] = *reinterpret_cast<const f16x8*>(&xstg[sb][s][c * LDX + kt * 32 + q * 8]);

        f32x4 acc[6], accx[2];
#pragma unroll
        for (int j = 0; j < 6; ++j) acc[j] = (f32x4){0, 0, 0, 0};
#pragma unroll
        for (int grp = 0; grp < 2; ++grp) accx[grp] = (f32x4){0, 0, 0, 0};
#pragma unroll
        for (int kt = 0; kt < 4; ++kt)
#pragma unroll
            for (int j = 0; j < 6; ++j) acc[j] = MFMA(ah[kt], whf[j][kt], acc[j]);
#pragma unroll
        for (int kt = 0; kt < 2; ++kt) {
#pragma unroll
            for (int j = 0; j < 4; ++j) acc[j] = MFMA(ax[kt], wxf[j][kt], acc[j]);
#pragma unroll
            for (int grp = 0; grp < 2; ++grp) accx[grp] = MFMA(ax[kt], wxf[4 + grp][kt], accx[grp]);
        }
#pragma unroll
        for (int grp = 0; grp < 2; ++grp) {
#pragma unroll
            for (int r4 = 0; r4 < 4; ++r4) {
                float rg = sigm(acc[grp][r4] + brz[grp]);
                float zg = sigm(acc[2 + grp][r4] + brz[2 + grp]);
                float hn = acc[4 + grp][r4] + bhn[grp];
                float xn = accx[grp][r4] + bxn[grp];
                float ng = tanha(fmaf(rg, hn, xn));
                float hv = fmaf(zg, hreg[grp][r4] - ng, ng);
                hreg[grp][r4] = hv;
                hbuf[cur ^ 1][(q * 4 + r4) * LDH + w * 16 + grp * 64 + c] = (f16)hv;
            }
        }
        if (s == 7 && ch + 1 < Tn / 8) {
#pragma unroll
            for (int i = 0; i < 8; ++i) {
                int f = (i * NTH + tid) * 4;
                int t_off = f >> 10, rem = f & 1023;
                int bb = rem >> 6, d = rem & 63;
                f16x4 h4;
                h4[0] = (f16)pre[i].x; h4[1] = (f16)pre[i].y;
                h4[2] = (f16)pre[i].z; h4[3] = (f16)pre[i].w;
                *reinterpret_cast<f16x4*>(&xstg[sb ^ 1][t_off][bb * LDX + d]) = h4;
            }
        }
        __syncthreads();
    }
#pragma unroll
    for (int grp = 0; grp < 2; ++grp)
#pragma unroll
        for (int r4 = 0; r4 < 4; ++r4)
            h_enc[(size_t)(b0 + q * 4 + r4) * Hn + w * 16 + grp * 64 + c] = hreg[grp][r4];
}

// ---------------- Generator GRU + fused readout (MFMA) ----------------
__global__ __launch_bounds__(NTH, 1)
void gen_kernel(const float* __restrict__ h_enc,
                const float* __restrict__ W_ic, const float* __restrict__ b_ic,
                const float* __restrict__ Wg_ih, const float* __restrict__ Wg_hh,
                const float* __restrict__ bg_ih, const float* __restrict__ bg_hh,
                const float* __restrict__ W_gf, const float* __restrict__ b_gf,
                const float* __restrict__ W_fr, const float* __restrict__ b_fr,
                float* __restrict__ out)
{
    const int b0 = blockIdx.x * BT;
    const int tid = threadIdx.x;
    const int w = tid >> 6, l = tid & 63, c = l & 15, q = l >> 4;

    __shared__ f16 hbuf[2][BT * LDH];
    __shared__ float hencs[BT][Hn];
    __shared__ float ics[BT][ICn];
    __shared__ float xpcs[BT][G3];
    __shared__ float fred[2][BT][4];

    for (int i = tid; i < BT * Hn; i += NTH)
        hencs[i >> 7][i & 127] = h_enc[(size_t)(b0 + (i >> 7)) * Hn + (i & 127)];
    __syncthreads();

    for (int i = tid; i < BT * ICn; i += NTH) {
        int bb = i / ICn, j = i - bb * ICn;
        float a = b_ic[j];
        const float* wr = W_ic + (size_t)j * Hn;
#pragma unroll 4
        for (int k = 0; k < Hn; ++k) a = fmaf(wr[k], hencs[bb][k], a);
        ics[bb][j] = a;
    }
    __syncthreads();

    for (int i = tid; i < BT * G3; i += NTH) {
        int g = i >> 4, bb = i & 15;
        float a = bg_ih[g];
        const float* wr = Wg_ih + (size_t)g * ICn;
#pragma unroll 4
        for (int k = 0; k < ICn; ++k) a = fmaf(wr[k], ics[bb][k], a);
        xpcs[bb][g] = a;
    }
    for (int i = tid; i < BT * Hn; i += NTH)
        hbuf[0][(i >> 7) * LDH + (i & 127)] = (f16)hencs[i >> 7][i & 127];

    f16x8 whf[6][4];
    int gidx[6];
#pragma unroll
    for (int j = 0; j < 6; ++j) {
        int g = (w + 4 * j) * 16 + c;
        gidx[j] = g;
#pragma unroll
        for (int kt = 0; kt < 4; ++kt) whf[j][kt] = ldw(Wg_hh, g, Hn, kt * 32 + q * 8);
    }
    f16x8 wgff[4];
#pragma unroll
    for (int kt = 0; kt < 4; ++kt) {
        if (c < 3) wgff[kt] = ldw(W_gf, c, Hn, kt * 32 + q * 8);
        else {
            f16x8 z;
#pragma unroll
            for (int j = 0; j < 8; ++j) z[j] = (f16)0.0f;
            wgff[kt] = z;
        }
    }
    const float bgfc = (c < 3) ? b_gf[c] : 0.0f;
    const int d = l;
    const float wfr0 = W_fr[d * 3 + 0], wfr1 = W_fr[d * 3 + 1], wfr2 = W_fr[d * 3 + 2];
    const float bfrd = b_fr[d];

    float hreg[2][4];
#pragma unroll
    for (int grp = 0; grp < 2; ++grp)
#pragma unroll
        for (int r4 = 0; r4 < 4; ++r4)
            hreg[grp][r4] = hencs[q * 4 + r4][w * 16 + grp * 64 + c];

    __syncthreads();  // xpcs + hbuf[0] ready

    float xrc[2][4], xzc[2][4], xnc[2][4], bhn[2];
#pragma unroll
    for (int grp = 0; grp < 2; ++grp) {
        const float bgr = bg_hh[gidx[grp]];
        const float bgz = bg_hh[gidx[2 + grp]];
        bhn[grp] = bg_hh[gidx[4 + grp]];
#pragma unroll
        for (int r4 = 0; r4 < 4; ++r4) {
            int bb = q * 4 + r4;
            xrc[grp][r4] = xpcs[bb][gidx[grp]] + bgr;
            xzc[grp][r4] = xpcs[bb][gidx[2 + grp]] + bgz;
            xnc[grp][r4] = xpcs[bb][gidx[4 + grp]];
        }
    }

    for (int t = 0; t < Tn; ++t) {
        const int cur = t & 1;
        f16x8 ah[4];
#pragma unroll
        for (int kt = 0; kt < 4; ++kt)
            ah[kt] = *reinterpret_cast<const f16x8*>(&hbuf[cur][c * LDH + kt * 32 + q * 8]);

        f32x4 acc[6];
#pragma unroll
        for (int j = 0; j < 6; ++j) acc[j] = (f32x4){0, 0, 0, 0};
#pragma unroll
        for (int kt = 0; kt < 4; ++kt)
#pragma unroll
            for (int j = 0; j < 6; ++j) acc[j] = MFMA(ah[kt], whf[j][kt], acc[j]);
        f32x4 facc = (f32x4){0, 0, 0, 0};
        if (w == 0) {
#pragma unroll
            for (int kt = 0; kt < 4; ++kt) facc = MFMA(ah[kt], wgff[kt], facc);
        }
#pragma unroll
        for (int grp = 0; grp < 2; ++grp) {
#pragma unroll
            for (int r4 = 0; r4 < 4; ++r4) {
                float rg = sigm(acc[grp][r4] + xrc[grp][r4]);
                float zg = sigm(acc[2 + grp][r4] + xzc[grp][r4]);
                float hn = acc[4 + grp][r4] + bhn[grp];
                float ng = tanha(fmaf(rg, hn, xnc[grp][r4]));
                float hv = fmaf(zg, hreg[grp][r4] - ng, ng);
                hreg[grp][r4] = hv;
                hbuf[cur ^ 1][(q * 4 + r4) * LDH + w * 16 + grp * 64 + c] = (f16)hv;
            }
        }
        if (w == 0 && c < 3) {
#pragma unroll
            for (int r4 = 0; r4 < 4; ++r4)
                fred[cur][q * 4 + r4][c] = __expf(facc[r4] + bgfc);
        }
        __syncthreads();
        if (t >= 1) {
            const int tout = t - 1;
#pragma unroll
            for (int rb = 0; rb < 4; ++rb) {
                int bb = w + rb * 4;
                float e0 = fred[cur][bb][0], e1 = fred[cur][bb][1], e2 = fred[cur][bb][2];
                float rate = bfrd + e0 * wfr0 + e1 * wfr1 + e2 * wfr2;
                out[((size_t)(b0 + bb) * Tn + tout) * Dn + d] = rate;
            }
        }
    }
    // epilogue: factors/rates for h_T (sits in hbuf[0] after t=1023)
    if (w == 0) {
        f16x8 ah[4];
#pragma unroll
        for (int kt = 0; kt < 4; ++kt)
            ah[kt] = *reinterpret_cast<const f16x8*>(&hbuf[0][c * LDH + kt * 32 + q * 8]);
        f32x4 facc = (f32x4){0, 0, 0, 0};
#pragma unroll
        for (int kt = 0; kt < 4; ++kt) facc = MFMA(ah[kt], wgff[kt], facc);
        if (c < 3) {
#pragma unroll
            for (int r4 = 0; r4 < 4; ++r4)
                fred[0][q * 4 + r4][c] = __expf(facc[r4] + bgfc);
        }
    }
    __syncthreads();
    {
#pragma unroll
        for (int rb = 0; rb < 4; ++rb) {
            int bb = w + rb * 4;
            float e0 = fred[0][bb][0], e1 = fred[0][bb][1], e2 = fred[0][bb][2];
            float rate = bfrd + e0 * wfr0 + e1 * wfr1 + e2 * wfr2;
            out[((size_t)(b0 + bb) * Tn + (Tn - 1)) * Dn + d] = rate;
        }
    }
}

extern "C" void kernel_launch(void* const* d_in, const int* in_sizes, int n_in,
                              void* d_out, int out_size, void* d_ws, size_t ws_size,
                              hipStream_t stream) {
    const float* mu    = (const float*)d_in[0];
    const float* We_ih = (const float*)d_in[1];
    const float* We_hh = (const float*)d_in[2];
    const float* be_ih = (const float*)d_in[3];
    const float* be_hh = (const float*)d_in[4];
    const float* W_ic  = (const float*)d_in[5];
    const float* b_ic  = (const float*)d_in[6];
    const float* Wg_ih = (const float*)d_in[7];
    const float* Wg_hh = (const float*)d_in[8];
    const float* bg_ih = (const float*)d_in[9];
    const float* bg_hh = (const float*)d_in[10];
    const float* W_gf  = (const float*)d_in[11];
    const float* b_gf  = (const float*)d_in[12];
    const float* W_fr  = (const float*)d_in[13];
    const float* b_fr  = (const float*)d_in[14];

    float* h_enc = (float*)d_ws;  // [B, H] f32 = 128 KiB
    float* out = (float*)d_out;

    enc_kernel<<<dim3(Bn / BT), dim3(NTH), 0, stream>>>(mu, We_ih, We_hh, be_ih, be_hh, h_enc);
    gen_kernel<<<dim3(Bn / BT), dim3(NTH), 0, stream>>>(h_enc, W_ic, b_ic, Wg_ih, Wg_hh,
                                                        bg_ih, bg_hh, W_gf, b_gf, W_fr, b_fr, out);
}

// Round 5
// 1612.604 us; speedup vs baseline: 1.9763x; 1.2106x over previous
//
#include <hip/hip_runtime.h>
#include <hip/hip_bf16.h>

#define Bn 256
#define Tn 1024
#define Dn 64
#define Hn 128
#define G3 384
#define ICn 100
#define BT 16
#define NTH 512
#define LDH 136
#define LDX 72

typedef _Float16 f16;
typedef __attribute__((ext_vector_type(8))) _Float16 f16x8;
typedef __attribute__((ext_vector_type(4))) _Float16 f16x4;
typedef __attribute__((ext_vector_type(4))) float f32x4;

#define MFMA(a, b, c) __builtin_amdgcn_mfma_f32_16x16x32_f16((a), (b), (c), 0, 0, 0)

__device__ __forceinline__ float rcpa(float x) { return __builtin_amdgcn_rcpf(x); }
__device__ __forceinline__ float sigm(float x) { return rcpa(1.0f + __expf(-x)); }
__device__ __forceinline__ float tanha(float x) {
    float t = __expf(-2.0f * x);
    return fmaf(2.0f, rcpa(1.0f + t), -1.0f);
}

// load a B^T fragment (8 contiguous k) from a row-major f32 weight, cvt to f16
__device__ __forceinline__ f16x8 ldw(const float* W, int row, int ldk, int k0) {
    const float* p = W + (size_t)row * ldk + k0;
    f16x8 r;
#pragma unroll
    for (int j = 0; j < 8; ++j) r[j] = (f16)p[j];
    return r;
}

// ---------------- Encoder GRU (MFMA, 8 waves) ----------------
// 16 WGs x 512 threads (8 waves, 2/SIMD). Wave w owns h-cols [w*16, w*16+16):
// gate rows r=w*16+c, z=128+w*16+c, n=256+w*16+c.
__global__ __launch_bounds__(NTH, 2)
void enc_kernel(const float* __restrict__ mu,
                const float* __restrict__ We_ih, const float* __restrict__ We_hh,
                const float* __restrict__ be_ih, const float* __restrict__ be_hh,
                float* __restrict__ h_enc)
{
    const int b0 = blockIdx.x * BT;
    const int tid = threadIdx.x;
    const int w = tid >> 6, l = tid & 63, c = l & 15, q = l >> 4;

    __shared__ f16 hbuf[2][BT * LDH];
    __shared__ f16 xstg[2][8][BT * LDX];

    const int gr = w * 16 + c, gz = Hn + w * 16 + c, gn = 2 * Hn + w * 16 + c;

    f16x8 whf[3][4], wxf[3][2];
#pragma unroll
    for (int kt = 0; kt < 4; ++kt) {
        whf[0][kt] = ldw(We_hh, gr, Hn, kt * 32 + q * 8);
        whf[1][kt] = ldw(We_hh, gz, Hn, kt * 32 + q * 8);
        whf[2][kt] = ldw(We_hh, gn, Hn, kt * 32 + q * 8);
    }
#pragma unroll
    for (int kt = 0; kt < 2; ++kt) {
        wxf[0][kt] = ldw(We_ih, gr, Dn, kt * 32 + q * 8);
        wxf[1][kt] = ldw(We_ih, gz, Dn, kt * 32 + q * 8);
        wxf[2][kt] = ldw(We_ih, gn, Dn, kt * 32 + q * 8);
    }
    const float brc = be_ih[gr] + be_hh[gr];
    const float bzc = be_ih[gz] + be_hh[gz];
    const float bxn = be_ih[gn];
    const float bhn = be_hh[gn];

    float hreg[4];
#pragma unroll
    for (int r4 = 0; r4 < 4; ++r4) hreg[r4] = 0.0f;
    for (int i = tid; i < BT * Hn; i += NTH) hbuf[0][(i >> 7) * LDH + (i & 127)] = (f16)0.0f;

    const int SIT = (BT * 8 * Dn) / (NTH * 4);  // staging iters per chunk = 4
    // stage chunk 0 (t = 0..7)
#pragma unroll
    for (int i = 0; i < SIT; ++i) {
        int f = (i * NTH + tid) * 4;
        int t_off = f >> 10, rem = f & 1023;
        int bb = rem >> 6, d = rem & 63;
        const float4 v = *reinterpret_cast<const float4*>(
            mu + ((size_t)(b0 + bb) * Tn + t_off) * Dn + d);
        f16x4 h4; h4[0] = (f16)v.x; h4[1] = (f16)v.y; h4[2] = (f16)v.z; h4[3] = (f16)v.w;
        *reinterpret_cast<f16x4*>(&xstg[0][t_off][bb * LDX + d]) = h4;
    }
    __syncthreads();

    float4 pre[SIT];
    for (int t = 0; t < Tn; ++t) {
        const int ch = t >> 3, s = t & 7, cur = t & 1, sb = ch & 1;
        if (s == 0 && ch + 1 < Tn / 8) {
#pragma unroll
            for (int i = 0; i < SIT; ++i) {
                int f = (i * NTH + tid) * 4;
                int t_off = f >> 10, rem = f & 1023;
                int bb = rem >> 6, d = rem & 63;
                pre[i] = *reinterpret_cast<const float4*>(
                    mu + ((size_t)(b0 + bb) * Tn + (ch + 1) * 8 + t_off) * Dn + d);
            }
        }
        f16x8 ah[4], ax[2];
#pragma unroll
        for (int kt = 0; kt < 4; ++kt)
            ah[kt] = *reinterpret_cast<const f16x8*>(&hbuf[cur][c * LDH + kt * 32 + q * 8]);
#pragma unroll
        for (int kt = 0; kt < 2; ++kt)
            ax[kt] = *reinterpret_cast<const f16x8*>(&xstg[sb][s][c * LDX + kt * 32 + q * 8]);

        f32x4 acc0 = (f32x4){0,0,0,0}, acc1 = (f32x4){0,0,0,0};
        f32x4 acc2 = (f32x4){0,0,0,0}, accx = (f32x4){0,0,0,0};
#pragma unroll
        for (int kt = 0; kt < 4; ++kt) {
            acc0 = MFMA(ah[kt], whf[0][kt], acc0);
            acc1 = MFMA(ah[kt], whf[1][kt], acc1);
            acc2 = MFMA(ah[kt], whf[2][kt], acc2);
        }
#pragma unroll
        for (int kt = 0; kt < 2; ++kt) {
            acc0 = MFMA(ax[kt], wxf[0][kt], acc0);
            acc1 = MFMA(ax[kt], wxf[1][kt], acc1);
            accx = MFMA(ax[kt], wxf[2][kt], accx);
        }
#pragma unroll
        for (int r4 = 0; r4 < 4; ++r4) {
            float rg = sigm(acc0[r4] + brc);
            float zg = sigm(acc1[r4] + bzc);
            float hn = acc2[r4] + bhn;
            float xn = accx[r4] + bxn;
            float ng = tanha(fmaf(rg, hn, xn));
            float hv = fmaf(zg, hreg[r4] - ng, ng);
            hreg[r4] = hv;
            hbuf[cur ^ 1][(q * 4 + r4) * LDH + w * 16 + c] = (f16)hv;
        }
        if (s == 7 && ch + 1 < Tn / 8) {
#pragma unroll
            for (int i = 0; i < SIT; ++i) {
                int f = (i * NTH + tid) * 4;
                int t_off = f >> 10, rem = f & 1023;
                int bb = rem >> 6, d = rem & 63;
                f16x4 h4;
                h4[0] = (f16)pre[i].x; h4[1] = (f16)pre[i].y;
                h4[2] = (f16)pre[i].z; h4[3] = (f16)pre[i].w;
                *reinterpret_cast<f16x4*>(&xstg[sb ^ 1][t_off][bb * LDX + d]) = h4;
            }
        }
        __syncthreads();
    }
#pragma unroll
    for (int r4 = 0; r4 < 4; ++r4)
        h_enc[(size_t)(b0 + q * 4 + r4) * Hn + w * 16 + c] = hreg[r4];
}

// ---------------- Generator GRU + fused readout (MFMA, 8 waves) ----------------
__global__ __launch_bounds__(NTH, 2)
void gen_kernel(const float* __restrict__ h_enc,
                const float* __restrict__ W_ic, const float* __restrict__ b_ic,
                const float* __restrict__ Wg_ih, const float* __restrict__ Wg_hh,
                const float* __restrict__ bg_ih, const float* __restrict__ bg_hh,
                const float* __restrict__ W_gf, const float* __restrict__ b_gf,
                const float* __restrict__ W_fr, const float* __restrict__ b_fr,
                float* __restrict__ out)
{
    const int b0 = blockIdx.x * BT;
    const int tid = threadIdx.x;
    const int w = tid >> 6, l = tid & 63, c = l & 15, q = l >> 4;

    __shared__ f16 hbuf[2][BT * LDH];
    __shared__ float hencs[BT][Hn];
    __shared__ float ics[BT][ICn];
    __shared__ float xpcs[BT][G3];
    __shared__ float fred[2][BT][4];

    for (int i = tid; i < BT * Hn; i += NTH)
        hencs[i >> 7][i & 127] = h_enc[(size_t)(b0 + (i >> 7)) * Hn + (i & 127)];
    __syncthreads();

    for (int i = tid; i < BT * ICn; i += NTH) {
        int bb = i / ICn, j = i - bb * ICn;
        float a = b_ic[j];
        const float* wr = W_ic + (size_t)j * Hn;
#pragma unroll 4
        for (int k = 0; k < Hn; ++k) a = fmaf(wr[k], hencs[bb][k], a);
        ics[bb][j] = a;
    }
    __syncthreads();

    for (int i = tid; i < BT * G3; i += NTH) {
        int g = i >> 4, bb = i & 15;
        float a = bg_ih[g];
        const float* wr = Wg_ih + (size_t)g * ICn;
#pragma unroll 4
        for (int k = 0; k < ICn; ++k) a = fmaf(wr[k], ics[bb][k], a);
        xpcs[bb][g] = a;
    }
    for (int i = tid; i < BT * Hn; i += NTH)
        hbuf[0][(i >> 7) * LDH + (i & 127)] = (f16)hencs[i >> 7][i & 127];

    const int gr = w * 16 + c, gz = Hn + w * 16 + c, gn = 2 * Hn + w * 16 + c;

    f16x8 whf[3][4];
#pragma unroll
    for (int kt = 0; kt < 4; ++kt) {
        whf[0][kt] = ldw(Wg_hh, gr, Hn, kt * 32 + q * 8);
        whf[1][kt] = ldw(Wg_hh, gz, Hn, kt * 32 + q * 8);
        whf[2][kt] = ldw(Wg_hh, gn, Hn, kt * 32 + q * 8);
    }
    f16x8 wgff[4];
    if (w == 0) {
#pragma unroll
        for (int kt = 0; kt < 4; ++kt) {
            if (c < 3) wgff[kt] = ldw(W_gf, c, Hn, kt * 32 + q * 8);
            else {
                f16x8 z;
#pragma unroll
                for (int j = 0; j < 8; ++j) z[j] = (f16)0.0f;
                wgff[kt] = z;
            }
        }
    }
    const float bgfc = (w == 0 && c < 3) ? b_gf[c] : 0.0f;
    const int d = l;
    const float wfr0 = W_fr[d * 3 + 0], wfr1 = W_fr[d * 3 + 1], wfr2 = W_fr[d * 3 + 2];
    const float bfrd = b_fr[d];

    float hreg[4];
#pragma unroll
    for (int r4 = 0; r4 < 4; ++r4) hreg[r4] = hencs[q * 4 + r4][w * 16 + c];

    __syncthreads();  // xpcs + hbuf[0] ready

    const float bgr = bg_hh[gr], bgz = bg_hh[gz], bhn = bg_hh[gn];
    float xrc[4], xzc[4], xnc[4];
#pragma unroll
    for (int r4 = 0; r4 < 4; ++r4) {
        int bb = q * 4 + r4;
        xrc[r4] = xpcs[bb][gr] + bgr;
        xzc[r4] = xpcs[bb][gz] + bgz;
        xnc[r4] = xpcs[bb][gn];
    }

    for (int t = 0; t < Tn; ++t) {
        const int cur = t & 1;
        f16x8 ah[4];
#pragma unroll
        for (int kt = 0; kt < 4; ++kt)
            ah[kt] = *reinterpret_cast<const f16x8*>(&hbuf[cur][c * LDH + kt * 32 + q * 8]);

        f32x4 acc0 = (f32x4){0,0,0,0}, acc1 = (f32x4){0,0,0,0}, acc2 = (f32x4){0,0,0,0};
#pragma unroll
        for (int kt = 0; kt < 4; ++kt) {
            acc0 = MFMA(ah[kt], whf[0][kt], acc0);
            acc1 = MFMA(ah[kt], whf[1][kt], acc1);
            acc2 = MFMA(ah[kt], whf[2][kt], acc2);
        }
        f32x4 facc = (f32x4){0, 0, 0, 0};
        if (w == 0) {
#pragma unroll
            for (int kt = 0; kt < 4; ++kt) facc = MFMA(ah[kt], wgff[kt], facc);
        }
#pragma unroll
        for (int r4 = 0; r4 < 4; ++r4) {
            float rg = sigm(acc0[r4] + xrc[r4]);
            float zg = sigm(acc1[r4] + xzc[r4]);
            float hn = acc2[r4] + bhn;
            float ng = tanha(fmaf(rg, hn, xnc[r4]));
            float hv = fmaf(zg, hreg[r4] - ng, ng);
            hreg[r4] = hv;
            hbuf[cur ^ 1][(q * 4 + r4) * LDH + w * 16 + c] = (f16)hv;
        }
        if (w == 0 && c < 3) {
#pragma unroll
            for (int r4 = 0; r4 < 4; ++r4)
                fred[cur][q * 4 + r4][c] = __expf(facc[r4] + bgfc);
        }
        __syncthreads();
        if (t >= 1) {
            const int tout = t - 1;
#pragma unroll
            for (int rb = 0; rb < 2; ++rb) {
                int bb = w + rb * 8;
                float e0 = fred[cur][bb][0], e1 = fred[cur][bb][1], e2 = fred[cur][bb][2];
                float rate = bfrd + e0 * wfr0 + e1 * wfr1 + e2 * wfr2;
                out[((size_t)(b0 + bb) * Tn + tout) * Dn + d] = rate;
            }
        }
    }
    // epilogue: factors/rates for h_T (sits in hbuf[0] after t=1023)
    if (w == 0) {
        f16x8 ah[4];
#pragma unroll
        for (int kt = 0; kt < 4; ++kt)
            ah[kt] = *reinterpret_cast<const f16x8*>(&hbuf[0][c * LDH + kt * 32 + q * 8]);
        f32x4 facc = (f32x4){0, 0, 0, 0};
#pragma unroll
        for (int kt = 0; kt < 4; ++kt) facc = MFMA(ah[kt], wgff[kt], facc);
        if (c < 3) {
#pragma unroll
            for (int r4 = 0; r4 < 4; ++r4)
                fred[0][q * 4 + r4][c] = __expf(facc[r4] + bgfc);
        }
    }
    __syncthreads();
    {
#pragma unroll
        for (int rb = 0; rb < 2; ++rb) {
            int bb = w + rb * 8;
            float e0 = fred[0][bb][0], e1 = fred[0][bb][1], e2 = fred[0][bb][2];
            float rate = bfrd + e0 * wfr0 + e1 * wfr1 + e2 * wfr2;
            out[((size_t)(b0 + bb) * Tn + (Tn - 1)) * Dn + d] = rate;
        }
    }
}

extern "C" void kernel_launch(void* const* d_in, const int* in_sizes, int n_in,
                              void* d_out, int out_size, void* d_ws, size_t ws_size,
                              hipStream_t stream) {
    const float* mu    = (const float*)d_in[0];
    const float* We_ih = (const float*)d_in[1];
    const float* We_hh = (const float*)d_in[2];
    const float* be_ih = (const float*)d_in[3];
    const float* be_hh = (const float*)d_in[4];
    const float* W_ic  = (const float*)d_in[5];
    const float* b_ic  = (const float*)d_in[6];
    const float* Wg_ih = (const float*)d_in[7];
    const float* Wg_hh = (const float*)d_in[8];
    const float* bg_ih = (const float*)d_in[9];
    const float* bg_hh = (const float*)d_in[10];
    const float* W_gf  = (const float*)d_in[11];
    const float* b_gf  = (const float*)d_in[12];
    const float* W_fr  = (const float*)d_in[13];
    const float* b_fr  = (const float*)d_in[14];

    float* h_enc = (float*)d_ws;  // [B, H] f32 = 128 KiB
    float* out = (float*)d_out;

    enc_kernel<<<dim3(Bn / BT), dim3(NTH), 0, stream>>>(mu, We_ih, We_hh, be_ih, be_hh, h_enc);
    gen_kernel<<<dim3(Bn / BT), dim3(NTH), 0, stream>>>(h_enc, W_ic, b_ic, Wg_ih, Wg_hh,
                                                        bg_ih, bg_hh, W_gf, b_gf, W_fr, b_fr, out);
}